// Round 4
// baseline (21.950 us; speedup 1.0000x reference)
//
#include <hip/hip_runtime.h>

#define HIDDEN 768
#define LN_EPS 1e-5f

typedef float f32x4 __attribute__((ext_vector_type(4)));

// Grid-stride ping-pong pipeline: each 64-lane wave owns rows
// {w, w+NW, w+2NW, ...}. While processing row in buffer A, the loads for the
// next row (ids + 9 float4 gathers) are already in flight into buffer B, so
// the L2/L3/HBM gather latency hides under the previous row's reduce+store.
__global__ __launch_bounds__(256) void bert_embedding_kernel(
    const int* __restrict__ input_ids,
    const int* __restrict__ token_type_ids,
    const float* __restrict__ tok_w,
    const float* __restrict__ pos_w,
    const float* __restrict__ type_w,
    const float* __restrict__ gamma,
    const float* __restrict__ beta,
    float* __restrict__ out,
    int n_rows, int S)
{
    const int lane = threadIdx.x & 63;
    const int wave = (blockIdx.x * blockDim.x + threadIdx.x) >> 6;
    const int NW   = (gridDim.x * blockDim.x) >> 6;
    if (wave >= n_rows) return;

    const int i0 = lane, i1 = lane + 64, i2 = lane + 128;

    const f32x4* __restrict__ g4 = reinterpret_cast<const f32x4*>(gamma);
    const f32x4* __restrict__ b4 = reinterpret_cast<const f32x4*>(beta);
    const f32x4 g0 = g4[i0], g1 = g4[i1], g2 = g4[i2];
    const f32x4 bb0 = b4[i0], bb1 = b4[i1], bb2 = b4[i2];

    auto LOAD = [&](int r, f32x4* a, f32x4* p, f32x4* c) {
        const int tok = input_ids[r];
        const int typ = token_type_ids[r];
        const int s   = r % S;
        const f32x4* __restrict__ tw = reinterpret_cast<const f32x4*>(tok_w  + (size_t)tok * HIDDEN);
        const f32x4* __restrict__ pw = reinterpret_cast<const f32x4*>(pos_w  + (size_t)s   * HIDDEN);
        const f32x4* __restrict__ yw = reinterpret_cast<const f32x4*>(type_w + (size_t)typ * HIDDEN);
        a[0] = tw[i0]; a[1] = tw[i1]; a[2] = tw[i2];
        p[0] = pw[i0]; p[1] = pw[i1]; p[2] = pw[i2];
        c[0] = yw[i0]; c[1] = yw[i1]; c[2] = yw[i2];
    };

    auto PROCESS = [&](int r, const f32x4* a, const f32x4* p, const f32x4* c) {
        const f32x4 e0 = a[0] + p[0] + c[0];
        const f32x4 e1 = a[1] + p[1] + c[1];
        const f32x4 e2 = a[2] + p[2] + c[2];
        float sum = e0.x + e0.y + e0.z + e0.w
                  + e1.x + e1.y + e1.z + e1.w
                  + e2.x + e2.y + e2.z + e2.w;
        float sq  = e0.x*e0.x + e0.y*e0.y + e0.z*e0.z + e0.w*e0.w
                  + e1.x*e1.x + e1.y*e1.y + e1.z*e1.z + e1.w*e1.w
                  + e2.x*e2.x + e2.y*e2.y + e2.z*e2.z + e2.w*e2.w;
        #pragma unroll
        for (int m = 1; m < 64; m <<= 1) {
            sum += __shfl_xor(sum, m);
            sq  += __shfl_xor(sq, m);
        }
        const float inv_h = 1.0f / (float)HIDDEN;
        const float mean = sum * inv_h;
        const float rs   = rsqrtf(sq * inv_h - mean * mean + LN_EPS);

        f32x4* __restrict__ o = reinterpret_cast<f32x4*>(out + (size_t)r * HIDDEN);
        f32x4 r0, r1, r2;
        r0.x = (e0.x - mean) * rs * g0.x + bb0.x;
        r0.y = (e0.y - mean) * rs * g0.y + bb0.y;
        r0.z = (e0.z - mean) * rs * g0.z + bb0.z;
        r0.w = (e0.w - mean) * rs * g0.w + bb0.w;
        r1.x = (e1.x - mean) * rs * g1.x + bb1.x;
        r1.y = (e1.y - mean) * rs * g1.y + bb1.y;
        r1.z = (e1.z - mean) * rs * g1.z + bb1.z;
        r1.w = (e1.w - mean) * rs * g1.w + bb1.w;
        r2.x = (e2.x - mean) * rs * g2.x + bb2.x;
        r2.y = (e2.y - mean) * rs * g2.y + bb2.y;
        r2.z = (e2.z - mean) * rs * g2.z + bb2.z;
        r2.w = (e2.w - mean) * rs * g2.w + bb2.w;
        __builtin_nontemporal_store(r0, &o[i0]);
        __builtin_nontemporal_store(r1, &o[i1]);
        __builtin_nontemporal_store(r2, &o[i2]);
    };

    // Ping-pong double buffer: loads for one buffer are in flight while the
    // other buffer is processed. All array indices are compile-time constant.
    f32x4 aA[3], pA[3], cA[3];
    f32x4 aB[3], pB[3], cB[3];

    int rA = wave;
    LOAD(rA, aA, pA, cA);
    int rB = rA + NW;
    while (true) {
        if (rB < n_rows) LOAD(rB, aB, pB, cB);
        PROCESS(rA, aA, pA, cA);
        rA = rB + NW;
        if (rB >= n_rows) break;
        if (rA < n_rows) LOAD(rA, aA, pA, cA);
        PROCESS(rB, aB, pB, cB);
        rB = rA + NW;
        if (rA >= n_rows) break;
    }
}

extern "C" void kernel_launch(void* const* d_in, const int* in_sizes, int n_in,
                              void* d_out, int out_size, void* d_ws, size_t ws_size,
                              hipStream_t stream) {
    const int*   input_ids      = (const int*)d_in[0];
    const int*   token_type_ids = (const int*)d_in[1];
    const float* tok_w          = (const float*)d_in[2];
    const float* pos_w          = (const float*)d_in[3];
    const float* type_w         = (const float*)d_in[4];
    const float* gamma          = (const float*)d_in[5];
    const float* beta           = (const float*)d_in[6];
    float* out = (float*)d_out;

    const int n_rows = in_sizes[0];          // B * S = 16384
    const int S = in_sizes[3] / HIDDEN;      // pos_w rows = 512

    // 2048 blocks x 4 waves = 8192 waves -> 2 rows per wave (pipeline depth 2).
    int waves_needed = (n_rows + 1) / 2;
    int blocks = (waves_needed + 3) / 4;
    if (blocks > 2048) blocks = 2048;
    if (blocks < 1) blocks = 1;
    bert_embedding_kernel<<<blocks, 256, 0, stream>>>(
        input_ids, token_type_ids, tok_w, pos_w, type_w, gamma, beta,
        out, n_rows, S);
}